// Round 4
// baseline (106.743 us; speedup 1.0000x reference)
//
#include <hip/hip_runtime.h>

// Problem constants (fixed by the reference): B=32, S=512, VDIM=256, MAX_LEN=13, 20 letters.
#define SLEN 512
#define VDIM 256
#define NBATCH 32
#define ML 13
#define NLET 20

#define BC 4              // b-chunks per s  -> grid = SLEN*BC blocks
#define NBB (NBATCH / BC) // 8 batches per block
#define XVP 272           // padded leading dim for x in LDS (mult of 16B; 272%32=16)
#define XSL (3 * XVP)     // floats per staged slice

// RES_LENS = {3,4,5,5,6,6,6,7,7,7,7,7,8,8,8,9,10,10,11,13} packed as nibbles.
// The reference hard-codes this table (gather_idx derives from it + seq), so
// off(s) = prefix-sum of len(seq[i]) replaces any gather/search.
#define LENS_LO 0x9888777776665543ULL   // letters 0..15
#define LENS_HI 0x000000000000DBAAULL   // letters 16..19

__device__ __forceinline__ int len_of(int L) {
    unsigned long long p = (L < 16) ? LENS_LO : LENS_HI;
    return (int)((p >> ((L & 15) * 4)) & 15ULL);
}

// ---------------------------------------------------------------------------
// Kernel 1: Wc[l][a][u] = sum_v W_out[l][a][v] * W_hid[l][v][u]   (17M MACs)
// grid (20, 16 u-chunks of 16), block 256 = 16 u-lanes x 16 v-splits
// -> 320 blocks (full chip). W_hid read exactly once (5.2 MB).
// ---------------------------------------------------------------------------
__global__ __launch_bounds__(256) void build_wc_kernel(
    const float* __restrict__ W_hid,   // (20, V, V)
    const float* __restrict__ W_out,   // (20, ML, V)
    float* __restrict__ Wc)            // (20, ML, V)  in d_ws
{
    const int l  = blockIdx.x;
    const int uq = blockIdx.y;         // 0..15
    const int t  = threadIdx.x;
    const int up = t & 15;
    const int vs = t >> 4;
    const int u  = uq * 16 + up;

    const float* wh = W_hid + (size_t)l * VDIM * VDIM;
    const float* wo = W_out + (size_t)l * ML * VDIM;

    float acc[ML];
#pragma unroll
    for (int a = 0; a < ML; ++a) acc[a] = 0.f;

#pragma unroll 4
    for (int vv = 0; vv < 16; ++vv) {
        const int v = vs * 16 + vv;
        const float h = wh[v * VDIM + u];
#pragma unroll
        for (int a = 0; a < ML; ++a)
            acc[a] += wo[a * VDIM + v] * h;
    }

    __shared__ float red[16][ML][16];  // 13.3 KB; 2-way alias = free
#pragma unroll
    for (int a = 0; a < ML; ++a) red[vs][a][up] = acc[a];
    __syncthreads();

    if (t < ML * 16) {
        const int a  = t >> 4;
        const int uu = t & 15;
        float ssum = 0.f;
#pragma unroll
        for (int vsl = 0; vsl < 16; ++vsl) ssum += red[vsl][a][uu];
        Wc[(l * ML + a) * VDIM + uq * 16 + uu] = ssum;
    }
}

// ---------------------------------------------------------------------------
// Kernel 2: out[b][off(s)+a][c] = sum_u Wc[seq[s]][a][u] * x[b][s][u][c]
// One block per (s, chunk of 8 batches), 192 threads.
// Thread slot: r = t&7 (8-wide u-split), c = (t>>3)%3, ap = (t>>3)/3 (0..6
// active). Each thread computes TWO atom rows (a=ap, a=ap+7) per x-read ->
// LDS read amplification 6.5x (was 13x). Wc fragments load straight from
// L2-resident Wc (no LDS stage). Two b-slices per iteration -> 4 barriers
// total, 4 float4 global loads in flight per thread.
// ---------------------------------------------------------------------------
__global__ __launch_bounds__(192) void decode_kernel(
    const float* __restrict__ x,       // (B, S, V, 3)
    const float* __restrict__ Wc,      // (20, ML, V)
    const int*   __restrict__ seq,     // (S)
    float* __restrict__ out,           // (B, NG, 3)
    const int NG)
{
    const int bx = blockIdx.x;
    const int s  = bx >> 2;            // / BC
    const int bc = bx & (BC - 1);
    const int t  = threadIdx.x;
    const int r  = t & 7;              // u-split lane 0..7
    const int sl = t >> 3;             // 0..23
    const int c  = sl % 3;
    const int ap = sl / 3;             // 0..7 (7 = idle)
    const int wv = t >> 6;             // wave 0..2

    __shared__ float xl[2][2][XSL];    // 13.1 KB: [parity][slice][c][u]
    __shared__ int   sredi[3];

    // --- issue x prefetches first (independent of everything) ---
    const int b0 = bc * NBB;
    const float* xs   = x + (size_t)s * (VDIM * 3);
    const size_t bstr = (size_t)SLEN * VDIM * 3;
    float4 pA0 = *reinterpret_cast<const float4*>(xs + (size_t)(b0 + 0) * bstr + t * 4);
    float4 pA1 = *reinterpret_cast<const float4*>(xs + (size_t)(b0 + 1) * bstr + t * 4);
    float4 pB0 = *reinterpret_cast<const float4*>(xs + (size_t)(b0 + 2) * bstr + t * 4);
    float4 pB1 = *reinterpret_cast<const float4*>(xs + (size_t)(b0 + 3) * bstr + t * 4);

    const int l = seq[s];              // uniform per block

    // --- Wc register fragments straight from L2 (266 KB, resident) ---
    const bool act = (ap < 7);
    const int  a0  = ap;
    float4 w0[8], w1[8];
#pragma unroll
    for (int i = 0; i < 8; ++i) { w0[i] = make_float4(0.f,0.f,0.f,0.f); w1[i] = w0[i]; }
    if (act) {
        const float* wb = Wc + ((size_t)l * ML + a0) * VDIM + r * 4;
#pragma unroll
        for (int i = 0; i < 8; ++i)
            w0[i] = *reinterpret_cast<const float4*>(wb + i * 32);
        if (ap < 6) {
            const float* wb1 = wb + 7 * VDIM;
#pragma unroll
            for (int i = 0; i < 8; ++i)
                w1[i] = *reinterpret_cast<const float4*>(wb1 + i * 32);
        }
    }

    // --- off(s) = sum_{i<s} len(seq[i]) : coalesced loads + wave reduce ---
    int part = 0;
    for (int gi = t; gi < s; gi += 192) part += len_of(seq[gi]);
#pragma unroll
    for (int d = 1; d < 64; d <<= 1) part += __shfl_xor(part, d);
    if ((t & 63) == 0) sredi[wv] = part;
    __syncthreads();
    const int off = sredi[0] + sredi[1] + sredi[2];
    const int len = len_of(l);

    for (int pi = 0; pi < NBB / 2; ++pi) {
        // --- stage pair (regs -> LDS, transposed (u,c) -> [c][u]) ---
        {
            float* d0 = xl[pi & 1][0];
            float* d1 = xl[pi & 1][1];
            const float vA[4] = {pA0.x, pA0.y, pA0.z, pA0.w};
            const float vB[4] = {pA1.x, pA1.y, pA1.z, pA1.w};
#pragma unroll
            for (int j = 0; j < 4; ++j) {
                const int idx = t * 4 + j;
                const int uu  = idx / 3;
                const int cc  = idx - uu * 3;
                d0[cc * XVP + uu] = vA[j];
                d1[cc * XVP + uu] = vB[j];
            }
        }
        pA0 = pB0; pA1 = pB1;
        if (pi + 2 < NBB / 2) {
            pB0 = *reinterpret_cast<const float4*>(xs + (size_t)(b0 + 2*pi + 4) * bstr + t * 4);
            pB1 = *reinterpret_cast<const float4*>(xs + (size_t)(b0 + 2*pi + 5) * bstr + t * 4);
        }
        __syncthreads();               // single barrier per pair

        if (act) {
#pragma unroll
            for (int j = 0; j < 2; ++j) {
                const float* xc = xl[pi & 1][j] + c * XVP + r * 4;
                float s0 = 0.f, s1 = 0.f;
#pragma unroll
                for (int i = 0; i < 8; ++i) {
                    const float4 xv = *reinterpret_cast<const float4*>(xc + i * 32);
                    s0 += w0[i].x * xv.x + w0[i].y * xv.y + w0[i].z * xv.z + w0[i].w * xv.w;
                    s1 += w1[i].x * xv.x + w1[i].y * xv.y + w1[i].z * xv.z + w1[i].w * xv.w;
                }
                // fold the 8-lane u-split (r = low 3 bits of lane id)
#pragma unroll
                for (int d = 1; d < 8; d <<= 1) {
                    s0 += __shfl_xor(s0, d);
                    s1 += __shfl_xor(s1, d);
                }
                if (r == 0) {
                    const int b = b0 + 2 * pi + j;
                    if (a0 < len)
                        out[((size_t)b * NG + off + a0) * 3 + c] = s0;
                    if (ap < 6 && a0 + 7 < len)
                        out[((size_t)b * NG + off + a0 + 7) * 3 + c] = s1;
                }
            }
        }
    }
}

extern "C" void kernel_launch(void* const* d_in, const int* in_sizes, int n_in,
                              void* d_out, int out_size, void* d_ws, size_t ws_size,
                              hipStream_t stream) {
    const float* x_v   = (const float*)d_in[0];   // (32,512,256,3) f32
    const float* W_hid = (const float*)d_in[1];   // (20,256,256)   f32
    const float* W_out = (const float*)d_in[2];   // (20,13,256)    f32
    const int*   seq   = (const int*)d_in[3];     // (512)          i32
    float*       out   = (float*)d_out;           // (32,3745,3)    f32
    float*       Wc    = (float*)d_ws;            // 266 KB scratch

    const int NG = in_sizes[4];                   // 3745 (gather_idx size)

    build_wc_kernel<<<dim3(NLET, 16), 256, 0, stream>>>(W_hid, W_out, Wc);
    decode_kernel<<<dim3(SLEN * BC), 192, 0, stream>>>(x_v, Wc, seq, out, NG);
}